// Round 9
// baseline (967.601 us; speedup 1.0000x reference)
//
#include <hip/hip_runtime.h>
#include <stdint.h>

#define BB 2
#define TT 1024
#define CC 2048
#define HH 32
#define NNH 64
#define FFD 8192
#define MTOT (BB*TT)    // 2048 rows
#define LNEPS 1e-5f
#define LOG2E 1.44269504088896340736f

typedef __attribute__((ext_vector_type(8))) __bf16 bf16x8;
typedef __attribute__((ext_vector_type(4))) float f32x4;

#define USE_GLL 1
typedef __attribute__((address_space(1))) void GAS;
typedef __attribute__((address_space(3))) void LAS;

__device__ inline void gload_lds16(const uint16_t* g, uint16_t* l) {
#if USE_GLL
  __builtin_amdgcn_global_load_lds((GAS*)g, (LAS*)l, 16, 0, 0);
#else
  *(uint4*)l = *(const uint4*)g;
#endif
}

__device__ inline float bf2f(uint32_t u) {
  union { uint32_t i; float f; } v; v.i = u << 16; return v.f;
}
__device__ inline uint16_t f2bf(float f) {
  union { float f; uint32_t i; } v; v.f = f;
  uint32_t r = v.i + 0x7FFFu + ((v.i >> 16) & 1u);
  return (uint16_t)(r >> 16);
}
__device__ inline void unpack8(uint4 d, float* v) {
  v[0] = bf2f(d.x & 0xffffu); v[1] = bf2f(d.x >> 16);
  v[2] = bf2f(d.y & 0xffffu); v[3] = bf2f(d.y >> 16);
  v[4] = bf2f(d.z & 0xffffu); v[5] = bf2f(d.z >> 16);
  v[6] = bf2f(d.w & 0xffffu); v[7] = bf2f(d.w >> 16);
}
__device__ inline uint4 pack8(const float* v) {
  uint4 d;
  d.x = (uint32_t)f2bf(v[0]) | ((uint32_t)f2bf(v[1]) << 16);
  d.y = (uint32_t)f2bf(v[2]) | ((uint32_t)f2bf(v[3]) << 16);
  d.z = (uint32_t)f2bf(v[4]) | ((uint32_t)f2bf(v[5]) << 16);
  d.w = (uint32_t)f2bf(v[6]) | ((uint32_t)f2bf(v[7]) << 16);
  return d;
}

// flag-aware loads for d_in buffers (fl=1 -> fp32, fl=0 -> bf16)
__device__ inline void load8f(const void* p, size_t idx, int fl, float* v) {
  if (fl) {
    const float* q = (const float*)p + idx;
    float4 a = *(const float4*)q; float4 b = *(const float4*)(q + 4);
    v[0]=a.x; v[1]=a.y; v[2]=a.z; v[3]=a.w; v[4]=b.x; v[5]=b.y; v[6]=b.z; v[7]=b.w;
  } else {
    unpack8(*(const uint4*)((const uint16_t*)p + idx), v);
  }
}
__device__ inline float load1f(const void* p, size_t idx, int fl) {
  return fl ? ((const float*)p)[idx] : bf2f(((const uint16_t*)p)[idx]);
}
__device__ inline void load4f(const void* p, size_t idx, int fl, float* v) {
  if (fl) {
    float4 a = *(const float4*)((const float*)p + idx);
    v[0]=a.x; v[1]=a.y; v[2]=a.z; v[3]=a.w;
  } else {
    ushort4 u = *(const ushort4*)((const uint16_t*)p + idx);
    v[0]=bf2f(u.x); v[1]=bf2f(u.y); v[2]=bf2f(u.z); v[3]=bf2f(u.w);
  }
}

// ---------------- dtype probe ----------------
__global__ void probe_kernel(const uint16_t* __restrict__ x, int* __restrict__ flag) {
  int tid = threadIdx.x; // 64
  float m = 0.f;
  for (int i = tid; i < 4096; i += 64) {
    float a = fabsf(bf2f(x[i]));
    if (a > m) m = a;
  }
  for (int o = 32; o; o >>= 1) { float t = __shfl_down(m, o); if (t > m) m = t; }
  if (tid == 0) *flag = (m > 1e6f) ? 1 : 0;
}

// ---------------- LayerNorm ----------------
template<int INMODE>
__global__ __launch_bounds__(256) void ln_kernel(const void* __restrict__ x,
    const void* __restrict__ g, const void* __restrict__ b,
    uint16_t* __restrict__ out, const int* __restrict__ dflag)
{
  int fl = *dflag;
  int row = blockIdx.x;
  int tid = threadIdx.x;
  int lane = tid & 63, wave = tid >> 6;
  size_t base = (size_t)row * CC + (size_t)tid * 8;
  float v[8];
  if constexpr (INMODE == 1) {
    const float* q = (const float*)x + base;
    float4 a = *(const float4*)q; float4 c = *(const float4*)(q + 4);
    v[0]=a.x; v[1]=a.y; v[2]=a.z; v[3]=a.w; v[4]=c.x; v[5]=c.y; v[6]=c.z; v[7]=c.w;
  } else {
    load8f(x, base, fl, v);
  }
  float s = 0.f, s2 = 0.f;
  #pragma unroll
  for (int j = 0; j < 8; j++) { s += v[j]; s2 += v[j] * v[j]; }
  for (int o = 32; o; o >>= 1) { s += __shfl_down(s, o); s2 += __shfl_down(s2, o); }
  __shared__ float red[8];
  if (lane == 0) { red[wave] = s; red[wave + 4] = s2; }
  __syncthreads();
  s  = red[0] + red[1] + red[2] + red[3];
  s2 = red[4] + red[5] + red[6] + red[7];
  float mean = s * (1.0f / CC);
  float var  = s2 * (1.0f / CC) - mean * mean;
  float rstd = rsqrtf(fmaxf(var, 0.f) + LNEPS);
  float gj[8], bj[8];
  load8f(g, (size_t)tid * 8, fl, gj);
  load8f(b, (size_t)tid * 8, fl, bj);
  float o8[8];
  #pragma unroll
  for (int j = 0; j < 8; j++) o8[j] = (v[j] - mean) * rstd * gj[j] + bj[j];
  *(uint4*)(out + base) = pack8(o8);
}

// ---------------- time-shift mixes ----------------
__global__ __launch_bounds__(256) void mix4_kernel(const uint16_t* __restrict__ xl,
    const void* __restrict__ tmr, const void* __restrict__ tmk,
    const void* __restrict__ tmv, const void* __restrict__ tmg,
    uint16_t* __restrict__ out, const int* __restrict__ dflag)
{
  int fl = *dflag;
  uint32_t idx = ((uint32_t)blockIdx.x * 256u + threadIdx.x) * 8u;
  uint32_t c = idx & (CC - 1);
  uint32_t row = idx >> 11;
  uint32_t t = row & (TT - 1);
  float xv[8], pv[8];
  unpack8(*(const uint4*)(xl + idx), xv);
  if (t) { unpack8(*(const uint4*)(xl + idx - CC), pv); }
  else   { for (int j = 0; j < 8; j++) pv[j] = 0.f; }
  const void* tms[4] = { tmr, tmk, tmv, tmg };
  const size_t SL = (size_t)MTOT * CC;
  #pragma unroll
  for (int a = 0; a < 4; a++) {
    float tm[8], o[8];
    load8f(tms[a], c, fl, tm);
    #pragma unroll
    for (int j = 0; j < 8; j++) o[j] = xv[j] * tm[j] + pv[j] * (1.f - tm[j]);
    *(uint4*)(out + a * SL + idx) = pack8(o);
  }
}

__global__ __launch_bounds__(256) void mix2_kernel(const uint16_t* __restrict__ xl,
    const void* __restrict__ tk, const void* __restrict__ tr,
    uint16_t* __restrict__ ok, uint16_t* __restrict__ orr,
    const int* __restrict__ dflag)
{
  int fl = *dflag;
  uint32_t idx = ((uint32_t)blockIdx.x * 256u + threadIdx.x) * 8u;
  uint32_t c = idx & (CC - 1);
  uint32_t row = idx >> 11;
  uint32_t t = row & (TT - 1);
  float xv[8], pv[8], tm[8], o[8];
  unpack8(*(const uint4*)(xl + idx), xv);
  if (t) { unpack8(*(const uint4*)(xl + idx - CC), pv); }
  else   { for (int j = 0; j < 8; j++) pv[j] = 0.f; }
  load8f(tk, c, fl, tm);
  #pragma unroll
  for (int j = 0; j < 8; j++) o[j] = xv[j] * tm[j] + pv[j] * (1.f - tm[j]);
  *(uint4*)(ok + idx) = pack8(o);
  load8f(tr, c, fl, tm);
  #pragma unroll
  for (int j = 0; j < 8; j++) o[j] = xv[j] * tm[j] + pv[j] * (1.f - tm[j]);
  *(uint4*)(orr + idx) = pack8(o);
}

// ---------------- weight transpose: W (Kd x Nd, d_in dtype) -> WT (Nd x Kd, bf16) ----------------
__device__ inline void transpose_tile(const void* W, uint16_t* WT, int Kd, int Nd,
                                      int n0, int k0, int fl, int tid)
{
  __shared__ __align__(16) uint16_t tile[64][66];
  int r = tid >> 3, s = tid & 7;
  #pragma unroll
  for (int p = 0; p < 2; p++) {
    int row = p * 32 + r;
    float tv[8];
    load8f(W, (size_t)(k0 + row) * Nd + n0 + s * 8, fl, tv);
    uint16_t* t = &tile[row][s * 8];
    #pragma unroll
    for (int e = 0; e < 8; e++) t[e] = f2bf(tv[e]);
  }
  __syncthreads();
  #pragma unroll
  for (int p = 0; p < 2; p++) {
    int row = p * 32 + r;
    uint16_t tmp[8];
    #pragma unroll
    for (int e = 0; e < 8; e++) tmp[e] = tile[s * 8 + e][row];
    uint4 o;
    o.x = (uint32_t)tmp[0] | ((uint32_t)tmp[1] << 16);
    o.y = (uint32_t)tmp[2] | ((uint32_t)tmp[3] << 16);
    o.z = (uint32_t)tmp[4] | ((uint32_t)tmp[5] << 16);
    o.w = (uint32_t)tmp[6] | ((uint32_t)tmp[7] << 16);
    *(uint4*)(WT + (size_t)(n0 + row) * Kd + k0 + s * 8) = o;
  }
}

__global__ __launch_bounds__(256) void transpose_kernel(const void* __restrict__ W,
    uint16_t* __restrict__ WT, int Kd, int Nd, const int* __restrict__ dflag)
{
  transpose_tile(W, WT, Kd, Nd, blockIdx.x * 64, blockIdx.y * 64, *dflag, threadIdx.x);
}

// 4 square CCxCC transposes in one launch (z selects)
__global__ __launch_bounds__(256) void transpose4_kernel(
    const void* __restrict__ W0, const void* __restrict__ W1,
    const void* __restrict__ W2, const void* __restrict__ W3,
    uint16_t* __restrict__ WT, const int* __restrict__ dflag)
{
  const void* Ws[4] = { W0, W1, W2, W3 };
  int z = blockIdx.z;
  transpose_tile(Ws[z], WT + (size_t)z * CC * CC, CC, CC,
                 blockIdx.x * 64, blockIdx.y * 64, *dflag, threadIdx.x);
}

// Wkey (2048x8192) -> WT  and  Wrec (2048x2048) -> WRECT, one launch (bx selects)
__global__ __launch_bounds__(256) void transpose_ff_kernel(
    const void* __restrict__ Wkey, const void* __restrict__ Wrec,
    uint16_t* __restrict__ WT, uint16_t* __restrict__ WRECT,
    const int* __restrict__ dflag)
{
  int fl = *dflag;
  int bx = blockIdx.x;
  if (bx < FFD / 64) {
    transpose_tile(Wkey, WT, CC, FFD, bx * 64, blockIdx.y * 64, fl, threadIdx.x);
  } else {
    transpose_tile(Wrec, WRECT, CC, CC, (bx - FFD / 64) * 64, blockIdx.y * 64, fl, threadIdx.x);
  }
}

// ---------------- small-tile GEMM (128x128, kept for low-parallelism cases) ----------------
enum { EPI_RESID = 2, EPI_SIGM = 9 };

template<int EPI>
__global__ __launch_bounds__(256, 2) void gemm_kernel(
    const uint16_t* __restrict__ Ain, const uint16_t* __restrict__ BTin,
    void* __restrict__ Cout, int N, int Kstride, int Kloop,
    const void* __restrict__ auxA, const int* __restrict__ dflag)
{
  const uint16_t* A  = Ain;
  const uint16_t* BT = BTin;
  uint16_t* co16 = (uint16_t*)Cout;
  float*    co32 = (float*)Cout;
  int fl = 0;
  if constexpr (EPI == EPI_RESID) fl = *dflag;
  int bx = blockIdx.x;
  int N_ = N;
  int n0 = bx * 128;
  int m0 = blockIdx.y * 128;
  __shared__ __align__(16) uint16_t As[128 * 64];
  __shared__ __align__(16) uint16_t Bs[128 * 64];
  int tid = threadIdx.x;
  int lane = tid & 63, wave = tid >> 6;
  int wm = (wave >> 1) * 64, wn = (wave & 1) * 64;
  int l15 = lane & 15, lq = lane >> 4;
  int sw = l15 & 7;
  f32x4 acc[4][4];
  #pragma unroll
  for (int i = 0; i < 4; i++)
    #pragma unroll
    for (int j = 0; j < 4; j++) acc[i][j] = 0.f;
  const int rr = tid >> 3, seg = tid & 7;
  const int sseg = (seg ^ (rr & 7)) * 8;   // swizzled k-group source
  const uint16_t* Ag = A + (size_t)(m0 + rr) * Kstride + sseg;
  const uint16_t* Bg = BT + (size_t)(n0 + rr) * Kstride + sseg;
  uint16_t* Asw = As + tid * 8;
  uint16_t* Bsw = Bs + tid * 8;
  for (int k0 = 0; k0 < Kloop; k0 += 64) {
    __syncthreads();
    #pragma unroll
    for (int p = 0; p < 4; p++) {
      gload_lds16(Ag + (size_t)p * 32 * Kstride + k0, Asw + p * 2048);
      gload_lds16(Bg + (size_t)p * 32 * Kstride + k0, Bsw + p * 2048);
    }
    __syncthreads();
    #pragma unroll
    for (int kk = 0; kk < 2; kk++) {
      int cidx = ((kk * 4 + lq) ^ sw) * 8;
      bf16x8 af[4], bv[4];
      #pragma unroll
      for (int f = 0; f < 4; f++) af[f] = *(const bf16x8*)&As[(wm + f * 16 + l15) * 64 + cidx];
      #pragma unroll
      for (int f = 0; f < 4; f++) bv[f] = *(const bf16x8*)&Bs[(wn + f * 16 + l15) * 64 + cidx];
      #pragma unroll
      for (int fm = 0; fm < 4; fm++)
        #pragma unroll
        for (int fn = 0; fn < 4; fn++)
          acc[fm][fn] = __builtin_amdgcn_mfma_f32_16x16x32_bf16(af[fm], bv[fn], acc[fm][fn], 0, 0, 0);
    }
  }
  #pragma unroll
  for (int fm = 0; fm < 4; fm++) {
    #pragma unroll
    for (int q = 0; q < 4; q++) {
      int gr = m0 + wm + fm * 16 + lq * 4 + q;
      size_t rowb = (size_t)gr * N_;
      #pragma unroll
      for (int fn = 0; fn < 4; fn++) {
        int gc = n0 + wn + fn * 16 + l15;
        size_t idx = rowb + gc;
        float val = acc[fm][fn][q];
        if constexpr (EPI == EPI_RESID) {
          co32[idx] = val + load1f(auxA, idx, fl);
        } else if constexpr (EPI == EPI_SIGM) {
          co16[idx] = f2bf(1.f / (1.f + __expf(-val)));
        }
      }
    }
  }
}

// ---------------- 256x256 4-barrier GEMM (T1..T5, plain HIP) ----------------
// BM=BN=256, BK=64, 8 waves (2M x 4N), 512 threads, 128 KiB LDS (2 dbuf x (A 32KB + B 32KB)).
// Quadrants per K-tile: Q1=(M0,N0) Q2=(M0,N1) Q3=(M1,N1) Q4=(M1,N0).
// R9: byte-identical to R6/R8 -- this kernel is the ENVIRONMENT PROBE. Identical source
// compiled to identical ISA measured 71.7 us (R6) vs 104.9 us (R8): the R7/R8 sessions'
// chips ran compute-bound code ~1.45x slower (memory-bound kernels unaffected). Expect
// ~72 us on a healthy chip, ~105 on a slow one; do NOT attribute the delta to code.
// R6 (kept): only the END-of-phase barrier (4 barriers/K-tile) -- waves skew inside a
// phase so early waves' MFMAs overlap late waves' LDS reads. +3% measured, refcheck'd.
// WAR ledger (end-of-phase barriers only):
//   A-h0(d): read P1 (drained pre-Q1), staged P2 (after P1-end bar) OK
//   B-h0(d): read P1 (drained pre-Q1), staged P3 OK
//   B-h1(d): read P1, drained pre-Q2 (P2), staged P4 (after P3-end bar) OK
//   A-h1(d^1): read P3 of t-1 (drained pre-Q3), staged P1 of t (after P4-end bar of t-1) OK
// RAW: boundary vmcnt(6) + P4-end barrier -- all of tile t+1 resident before any wave
// enters tile t+1; 6 of t+2's loads stay in flight.
// XCD swizzle (T1): measured FETCH 147.6 -> 49.3 MB. LDS XOR swizzle (T2): 0 bank conflicts.
enum { G_RKVG = 0, G_KK = 1, G_PART = 2 };

template<int EPI>
__global__ __launch_bounds__(512, 2) void gemm256_kernel(
    const uint16_t* __restrict__ Ain, const uint16_t* __restrict__ BTin,
    void* __restrict__ Cout, int N, int Kstride, int Kloop, int cx,
    float* __restrict__ p2, float* __restrict__ p3a, float* __restrict__ p3b)
{
  __shared__ __align__(16) uint16_t smem[65536];   // A: [0,32768) B: [32768,65536) elements
  const uint16_t* A  = Ain;
  const uint16_t* BT = BTin;
  uint16_t* co16 = (uint16_t*)Cout;
  float*    co32 = (float*)Cout;

  // ---- XCD-aware bijective remap (nwg == 256 for all call sites) ----
  uint32_t lid = ((uint32_t)blockIdx.z * gridDim.y + blockIdx.y) * gridDim.x + blockIdx.x;
  uint32_t xcd = lid & 7u, s = lid >> 3;          // s in [0,32)
  uint32_t lx = s % (uint32_t)cx, ly = s / (uint32_t)cx;
  uint32_t sx = gridDim.x / (uint32_t)cx;         // chunks along x
  uint32_t cxi = xcd % sx, cyi = xcd / sx;
  uint32_t gx  = cxi * (uint32_t)cx + lx;         // n-tile
  uint32_t gyz = cyi * (32u / (uint32_t)cx) + ly; // flattened (z*GY + y)
  uint32_t gy  = gyz % gridDim.y;
  uint32_t z   = gyz / gridDim.y;

  int n0 = (int)gx * 256;
  int m0 = (int)gy * 256;
  bool silu = false;
  if constexpr (EPI == G_RKVG) {
    A    += (size_t)z * MTOT * CC;
    BT   += (size_t)z * CC * CC;
    co16 += (size_t)z * MTOT * CC;
    silu = (z == 3);
  }
  if constexpr (EPI == G_PART) {
    A  += (size_t)z * Kloop;      // column offset into K
    BT += (size_t)z * Kloop;
    if (z < 2)      co32 += (size_t)z * MTOT * 2048;
    else if (z == 2) co32 = p2;
    else            co32 = (m0 < 1024) ? p3a : (p3b - (size_t)1024 * 2048);
  }
  const int tid  = threadIdx.x;
  const int lane = tid & 63, wave = tid >> 6;
  const int wm = wave >> 2;          // 0..1
  const int wn = wave & 3;           // 0..3
  const int l15 = lane & 15, lq = lane >> 4;
  const int sw = l15 & 7;
  const int c0 = ((0 * 4 + lq) ^ sw) * 8;
  const int c1 = ((1 * 4 + lq) ^ sw) * 8;

  // staging addressing: thread covers rows (tid>>3) and (tid>>3)+64 of a 128-row half-tile,
  // segment tid&7, source k-group pre-swizzled by row&7 (row&7 == (tid>>3)&7 for both rows).
  const int trow = tid >> 3;
  const int tswz = ((tid & 7) ^ (trow & 7)) * 8;
  const uint16_t* Ag = A  + ((size_t)m0 + trow) * Kstride + tswz;
  const uint16_t* Bg = BT + ((size_t)n0 + trow) * Kstride + tswz;
  uint16_t* ldsT = smem + tid * 8;
  const size_t r64K = (size_t)64 * Kstride;

  const uint16_t* aRd = smem + (wm * 64 + l15) * 64;
  const uint16_t* bRd = smem + 32768 + (wn * 32 + l15) * 64;

  bf16x8 a[4][2];
  bf16x8 bb[2][2][2];
  f32x4  acc[2][4][2][2];
  #pragma unroll
  for (int mh = 0; mh < 2; mh++)
    #pragma unroll
    for (int f = 0; f < 4; f++)
      #pragma unroll
      for (int nh = 0; nh < 2; nh++)
        #pragma unroll
        for (int g = 0; g < 2; g++) acc[mh][f][nh][g] = 0.f;

#define STG(Mg, matOff, d, h, kt) do { \
    const uint16_t* s_ = (Mg) + (size_t)((h) * 128) * Kstride + (size_t)(kt) * 64; \
    uint16_t* l_ = ldsT + (matOff) + (d) * 16384 + (h) * 8192; \
    gload_lds16(s_, l_); \
    gload_lds16(s_ + r64K, l_ + 4096); \
  } while (0)

#define RD_A(mh, d) do { \
    const uint16_t* p_ = aRd + (d) * 16384 + (mh) * 8192; \
    _Pragma("unroll") \
    for (int f = 0; f < 4; f++) { \
      a[f][0] = *(const bf16x8*)(p_ + f * 1024 + c0); \
      a[f][1] = *(const bf16x8*)(p_ + f * 1024 + c1); \
    } \
  } while (0)

#define RD_B(nh, d) do { \
    const uint16_t* p_ = bRd + (d) * 16384 + (nh) * 8192; \
    _Pragma("unroll") \
    for (int g = 0; g < 2; g++) { \
      bb[nh][g][0] = *(const bf16x8*)(p_ + g * 1024 + c0); \
      bb[nh][g][1] = *(const bf16x8*)(p_ + g * 1024 + c1); \
    } \
  } while (0)

#define QUAD(mh, nh) do { \
    __builtin_amdgcn_s_setprio(1); \
    _Pragma("unroll") \
    for (int f = 0; f < 4; f++) \
      _Pragma("unroll") \
      for (int g = 0; g < 2; g++) { \
        acc[mh][f][nh][g] = __builtin_amdgcn_mfma_f32_16x16x32_bf16(a[f][0], bb[nh][g][0], acc[mh][f][nh][g], 0, 0, 0); \
        acc[mh][f][nh][g] = __builtin_amdgcn_mfma_f32_16x16x32_bf16(a[f][1], bb[nh][g][1], acc[mh][f][nh][g], 0, 0, 0); \
      } \
    __builtin_amdgcn_s_setprio(0); \
  } while (0)

#define TILE(t, d) do { \
    /* P1: Q1=(M0,N0) -- read a0/b0 (needed) then b1 early; stage t+1.A-h1 -> d^1 */ \
    RD_A(0, d); RD_B(0, d); \
    __builtin_amdgcn_sched_barrier(0); \
    RD_B(1, d); \
    if ((t) + 1 < NT) STG(Ag, 0, (d) ^ 1, 1, (t) + 1); \
    QUAD(0, 0); \
    __builtin_amdgcn_s_barrier(); \
    /* P2: Q2=(M0,N1) -- stage t+2.A-h0 (readers drained, certified by P1-end bar) */ \
    if ((t) + 2 < NT) STG(Ag, 0, d, 0, (t) + 2); \
    QUAD(0, 1); \
    __builtin_amdgcn_s_barrier(); \
    /* P3: Q3=(M1,N1) -- read A1; stage t+2.B-h0 (readers drained pre-Q1, cert. P1-end) */ \
    RD_A(1, d); \
    if ((t) + 2 < NT) STG(Bg, 32768, d, 0, (t) + 2); \
    QUAD(1, 1); \
    __builtin_amdgcn_s_barrier(); \
    /* P4: Q4=(M1,N0) -- bb[0] persists from P1; stage t+2.B-h1 (b1 drained pre-Q2) */ \
    if ((t) + 2 < NT) STG(Bg, 32768, d, 1, (t) + 2); \
    QUAD(1, 0); \
    if ((t) + 2 < NT)      { asm volatile("s_waitcnt vmcnt(6)" ::: "memory"); } \
    else if ((t) + 1 < NT) { asm volatile("s_waitcnt vmcnt(0)" ::: "memory"); } \
    __builtin_amdgcn_s_barrier(); \
  } while (0)

  const int NT = Kloop >> 6;   // always even (>= 32) for all call sites
  // prologue: tile0 fully (4 half-tiles) + tile1 partial (3; A-h1 deferred to ph1 of tile0)
  STG(Ag, 0, 0, 0, 0); STG(Ag, 0, 0, 1, 0);
  STG(Bg, 32768, 0, 0, 0); STG(Bg, 32768, 0, 1, 0);
  if (NT > 1) {
    STG(Ag, 0, 1, 0, 1); STG(Bg, 32768, 1, 0, 1); STG(Bg, 32768, 1, 1, 1);
    asm volatile("s_waitcnt vmcnt(6)" ::: "memory");   // tile0's 8 loads landed
  } else {
    asm volatile("s_waitcnt vmcnt(0)" ::: "memory");
  }
  __builtin_amdgcn_s_barrier();

  for (int t = 0; t < NT; t += 2) {
    TILE(t, 0);
    TILE(t + 1, 1);
  }

#undef TILE
#undef QUAD
#undef RD_B
#undef RD_A
#undef STG

  // epilogue
  #pragma unroll
  for (int mh = 0; mh < 2; mh++) {
    #pragma unroll
    for (int f = 0; f < 4; f++) {
      #pragma unroll
      for (int q = 0; q < 4; q++) {
        int gr = m0 + mh * 128 + wm * 64 + f * 16 + lq * 4 + q;
        size_t rowb = (size_t)gr * N;
        #pragma unroll
        for (int nh = 0; nh < 2; nh++) {
          #pragma unroll
          for (int g = 0; g < 2; g++) {
            int gc = n0 + nh * 128 + wn * 32 + g * 16 + l15;
            size_t idx = rowb + gc;
            float val = acc[mh][f][nh][g][q];
            if constexpr (EPI == G_RKVG) {
              if (silu) val = val / (1.f + __expf(-fmaxf(val, -80.f)));
              co16[idx] = f2bf(val);
            } else if constexpr (EPI == G_KK) {
              float tv = fmaxf(val, 0.f);
              co16[idx] = f2bf(tv * tv);
            } else if constexpr (EPI == G_PART) {
              co32[idx] = val;
            }
          }
        }
      }
    }
  }
}

// ---------------- split-K reduce + final epilogue ----------------
__global__ __launch_bounds__(256) void final_reduce_kernel(
    const float* __restrict__ P, const float* __restrict__ x1,
    const uint16_t* __restrict__ sr, void* __restrict__ out,
    const float* __restrict__ P2, const float* __restrict__ P3a,
    const float* __restrict__ P3b, const int* __restrict__ dflag)
{
  int fl = *dflag;
  size_t idx = ((size_t)blockIdx.x * 256 + threadIdx.x) * 8;
  const float* P1 = P + (size_t)MTOT * 2048;
  const float* P3 = (idx < (size_t)1024 * 2048) ? (P3a + idx) : (P3b + idx - (size_t)1024 * 2048);
  float a[8], b[8], c2[8], d3[8], xv[8], s8[8], o[8];
  { float4 t0 = *(const float4*)(P + idx);  float4 t1 = *(const float4*)(P + idx + 4);
    a[0]=t0.x;a[1]=t0.y;a[2]=t0.z;a[3]=t0.w;a[4]=t1.x;a[5]=t1.y;a[6]=t1.z;a[7]=t1.w; }
  { float4 t0 = *(const float4*)(P1 + idx); float4 t1 = *(const float4*)(P1 + idx + 4);
    b[0]=t0.x;b[1]=t0.y;b[2]=t0.z;b[3]=t0.w;b[4]=t1.x;b[5]=t1.y;b[6]=t1.z;b[7]=t1.w; }
  { float4 t0 = *(const float4*)(P2 + idx); float4 t1 = *(const float4*)(P2 + idx + 4);
    c2[0]=t0.x;c2[1]=t0.y;c2[2]=t0.z;c2[3]=t0.w;c2[4]=t1.x;c2[5]=t1.y;c2[6]=t1.z;c2[7]=t1.w; }
  { float4 t0 = *(const float4*)(P3);       float4 t1 = *(const float4*)(P3 + 4);
    d3[0]=t0.x;d3[1]=t0.y;d3[2]=t0.z;d3[3]=t0.w;d3[4]=t1.x;d3[5]=t1.y;d3[6]=t1.z;d3[7]=t1.w; }
  { float4 t0 = *(const float4*)(x1 + idx); float4 t1 = *(const float4*)(x1 + idx + 4);
    xv[0]=t0.x;xv[1]=t0.y;xv[2]=t0.z;xv[3]=t0.w;xv[4]=t1.x;xv[5]=t1.y;xv[6]=t1.z;xv[7]=t1.w; }
  unpack8(*(const uint4*)(sr + idx), s8);
  #pragma unroll
  for (int j = 0; j < 8; j++) o[j] = xv[j] + s8[j] * (a[j] + b[j] + c2[j] + d3[j]);
  if (fl) {
    float* q = (float*)out + idx;
    *(float4*)q = make_float4(o[0], o[1], o[2], o[3]);
    *(float4*)(q + 4) = make_float4(o[4], o[5], o[6], o[7]);
  } else {
    *(uint4*)((uint16_t*)out + idx) = pack8(o);
  }
}

// ---------------- WKV5 chunked ----------------
__global__ __launch_bounds__(256) void wkv_p_kernel(
    const uint16_t* __restrict__ kq, const uint16_t* __restrict__ vq,
    const void* __restrict__ wq, float* __restrict__ P,
    const int* __restrict__ dflag)
{
  int fl = *dflag;
  int blk = blockIdx.x;
  int c = blk & 15, h = (blk >> 4) & 31, b = blk >> 9;
  __shared__ __align__(16) float Kt[64][64];
  __shared__ __align__(16) uint16_t Vb[64][64];
  __shared__ __align__(16) float e_s[64];
  int tid = threadIdx.x;
  if (tid < 64) e_s[tid] = fminf(__expf(load1f(wq, h * 64 + tid, fl)), 100.f);
  __syncthreads();
  int rr = tid >> 3, cs = (tid & 7) * 8;
  #pragma unroll
  for (int p = 0; p < 2; p++) {
    int s = p * 32 + rr;
    size_t gbase = ((size_t)(b * TT + c * 64 + s)) * CC + h * 64 + cs;
    float k8[8];
    unpack8(*(const uint4*)(kq + gbase), k8);
    float sp = (float)(s + 1) * LOG2E;
    #pragma unroll
    for (int j = 0; j < 8; j++) Kt[s][cs + j] = k8[j] * exp2f(fminf(sp * e_s[cs + j], 80.f));
    *(uint4*)&Vb[s][cs] = *(const uint4*)(vq + gbase);
  }
  __syncthreads();
  int tx = tid & 15, ty = tid >> 4;
  int i0 = ty * 4, j0 = tx * 4;
  float acc[4][4] = {};
  for (int s = 0; s < 64; s++) {
    float4 a = *(const float4*)&Kt[s][i0];
    ushort4 vv = *(const ushort4*)&Vb[s][j0];
    float b0 = bf2f(vv.x), b1 = bf2f(vv.y), b2 = bf2f(vv.z), b3 = bf2f(vv.w);
    float am[4] = { a.x, a.y, a.z, a.w };
    #pragma unroll
    for (int m = 0; m < 4; m++) {
      acc[m][0] += am[m] * b0; acc[m][1] += am[m] * b1;
      acc[m][2] += am[m] * b2; acc[m][3] += am[m] * b3;
    }
  }
  float* Pb = P + (size_t)blk * 4096;
  #pragma unroll
  for (int m = 0; m < 4; m++) {
    float dl = exp2f(-64.0f * LOG2E * e_s[i0 + m]);
    float4 o = { acc[m][0] * dl, acc[m][1] * dl, acc[m][2] * dl, acc[m][3] * dl };
    *(float4*)&Pb[(i0 + m) * 64 + j0] = o;
  }
}

// parallel scan -- one float4 chain per thread, 256 blocks.
__global__ __launch_bounds__(256) void wkv_s_kernel(const float* __restrict__ P,
    const void* __restrict__ wq, float* __restrict__ S,
    const int* __restrict__ dflag)
{
  int fl = *dflag;
  int bh = blockIdx.x >> 2;      // 0..63
  int part = blockIdx.x & 3;     // 0..3
  int h = bh & 31;
  int tid = threadIdx.x;
  int e = part * 1024 + tid * 4; // float4 offset within 4096-elem state
  int i = e >> 6;                // state row (dl depends only on i)
  float ex = fminf(__expf(load1f(wq, h * 64 + i, fl)), 100.f);
  float dl = exp2f(-64.0f * LOG2E * ex);
  float4 s4 = {0.f, 0.f, 0.f, 0.f};
  size_t base = (size_t)bh * 16 * 4096 + e;
  #pragma unroll 4
  for (int c = 0; c < 16; c++) {
    *(float4*)&S[base] = s4;
    float4 p4 = *(const float4*)&P[base];
    s4 = make_float4(dl * s4.x + p4.x, dl * s4.y + p4.y, dl * s4.z + p4.z, dl * s4.w + p4.w);
    base += 4096;
  }
}

// R9: GroupNorm(att/8)*g FUSED into the epilogue (gn_mul kernel deleted). The GN group is
// the 64 channels of head h at one (b,t) -- exactly one output row of this block. Threads
// sharing ty hold all 64 cols of row t0+m (4 each, 16 contiguous lanes) -> mean/var via
// local 4-sum + __shfl_xor 1/2/4/8. Eliminates the 67 MB f32 ATT round-trip + one launch.
// R8 (kept): Rt/Kt/Ss padded to [64][68] -- kills the 16-way same-bank column read
// (bank was i%32 for all lanes at stride 64; stride 68 varies bank with row).
__global__ __launch_bounds__(256, 2) void wkv_y_kernel(
    const uint16_t* __restrict__ rq, const uint16_t* __restrict__ kq,
    const uint16_t* __restrict__ vq, const void* __restrict__ wq,
    const void* __restrict__ uq, const float* __restrict__ S,
    const void* __restrict__ lnxg, const void* __restrict__ lnxb,
    const uint16_t* __restrict__ gate, uint16_t* __restrict__ outp,
    const int* __restrict__ dflag)
{
  int fl = *dflag;
  int blk = blockIdx.x;
  int c = blk & 15, h = (blk >> 4) & 31, b = blk >> 9;
  __shared__ __align__(16) float Rt[64][68];
  __shared__ __align__(16) float Kt[64][68];
  __shared__ __align__(16) uint16_t Vb[64][64];
  __shared__ __align__(16) float Ss[64][68];
  __shared__ __align__(16) float e_s[64];
  __shared__ __align__(16) float ud_s[64];
  int tid = threadIdx.x;
  if (tid < 64) {
    float e = fminf(__expf(load1f(wq, h * 64 + tid, fl)), 100.f);
    e_s[tid] = e;
    ud_s[tid] = load1f(uq, h * 64 + tid, fl) * __expf(-e);
  }
  __syncthreads();
  int rr = tid >> 3, cs = (tid & 7) * 8;
  #pragma unroll
  for (int p = 0; p < 2; p++) {
    int s = p * 32 + rr;
    size_t gbase = ((size_t)(b * TT + c * 64 + s)) * CC + h * 64 + cs;
    float r8[8], k8[8];
    unpack8(*(const uint4*)(rq + gbase), r8);
    unpack8(*(const uint4*)(kq + gbase), k8);
    float tneg = -(float)s * LOG2E;
    float spos = (float)(s + 1) * LOG2E;
    #pragma unroll
    for (int j = 0; j < 8; j++) {
      float e = e_s[cs + j];
      Rt[s][cs + j] = r8[j] * exp2f(tneg * e);
      Kt[s][cs + j] = k8[j] * exp2f(fminf(spos * e, 80.f));
    }
    *(uint4*)&Vb[s][cs] = *(const uint4*)(vq + gbase);
  }
  {
    int r2 = tid >> 2, q = tid & 3;
    const float* Sbp = S + (size_t)blk * 4096 + (size_t)r2 * 64 + q * 16;
    *(float4*)&Ss[r2][q * 16 + 0]  = *(const float4*)&Sbp[0];
    *(float4*)&Ss[r2][q * 16 + 4]  = *(const float4*)&Sbp[4];
    *(float4*)&Ss[r2][q * 16 + 8]  = *(const float4*)&Sbp[8];
    *(float4*)&Ss[r2][q * 16 + 12] = *(const float4*)&Sbp[12];
  }
  __syncthreads();
  int tx = tid & 15, ty = tid >> 4;
  int t0 = ty * 4, s0 = tx * 4;
  float acc[4][4] = {};
  for (int iq = 0; iq < 16; iq++) {
    int i = iq * 4;
    float4 ra[4], kb[4];
    #pragma unroll
    for (int m = 0; m < 4; m++) ra[m] = *(const float4*)&Rt[t0 + m][i];
    #pragma unroll
    for (int n = 0; n < 4; n++) kb[n] = *(const float4*)&Kt[s0 + n][i];
    #pragma unroll
    for (int m = 0; m < 4; m++)
      #pragma unroll
      for (int n = 0; n < 4; n++)
        acc[m][n] += ra[m].x * kb[n].x + ra[m].y * kb[n].y + ra[m].z * kb[n].z + ra[m].w * kb[n].w;
  }
  float dg = 0.f;
  if (tid < 64) {
    for (int iq = 0; iq < 16; iq++) {
      int i = iq * 4;
      float4 a = *(const float4*)&Rt[tid][i];
      float4 kk = *(const float4*)&Kt[tid][i];
      float4 u4 = *(const float4*)&ud_s[i];
      dg += a.x * kk.x * u4.x + a.y * kk.y * u4.y + a.z * kk.z * u4.z + a.w * kk.w * u4.w;
    }
  }
  __syncthreads();
  #pragma unroll
  for (int m = 0; m < 4; m++)
    #pragma unroll
    for (int n = 0; n < 4; n++) {
      int t = t0 + m, s = s0 + n;
      Kt[t][s] = (s < t) ? acc[m][n] : 0.0f;
    }
  __syncthreads();
  if (tid < 64) Kt[tid][tid] = dg;
  __syncthreads();
  int j0 = tx * 4;
  float y[4][4] = {};
  for (int sq = 0; sq < 16; sq++) {
    int s = sq * 4;
    float4 a4[4];
    #pragma unroll
    for (int m = 0; m < 4; m++) a4[m] = *(const float4*)&Kt[t0 + m][s];
    float vb[4][4];
    #pragma unroll
    for (int qq = 0; qq < 4; qq++) {
      ushort4 vv = *(const ushort4*)&Vb[s + qq][j0];
      vb[qq][0] = bf2f(vv.x); vb[qq][1] = bf2f(vv.y); vb[qq][2] = bf2f(vv.z); vb[qq][3] = bf2f(vv.w);
    }
    #pragma unroll
    for (int m = 0; m < 4; m++)
      #pragma unroll
      for (int n = 0; n < 4; n++)
        y[m][n] += a4[m].x * vb[0][n] + a4[m].y * vb[1][n] + a4[m].z * vb[2][n] + a4[m].w * vb[3][n];
  }
  for (int iq = 0; iq < 16; iq++) {
    int i = iq * 4;
    float4 r4[4], s4[4];
    #pragma unroll
    for (int m = 0; m < 4; m++) r4[m] = *(const float4*)&Rt[t0 + m][i];
    #pragma unroll
    for (int qq = 0; qq < 4; qq++) s4[qq] = *(const float4*)&Ss[i + qq][j0];
    #pragma unroll
    for (int m = 0; m < 4; m++)
      #pragma unroll
      for (int n = 0; n < 4; n++)
        y[m][n] += r4[m].x * s4[0][n] + r4[m].y * s4[1][n] + r4[m].z * s4[2][n] + r4[m].w * s4[3][n];
  }
  // ---- fused GroupNorm(att/8) * gate, write bf16 ----
  float g4[4], b4[4];
  load4f(lnxg, (size_t)(h * 64 + j0), fl, g4);
  load4f(lnxb, (size_t)(h * 64 + j0), fl, b4);
  #pragma unroll
  for (int m = 0; m < 4; m++) {
    float vv[4];
    #pragma unroll
    for (int n = 0; n < 4; n++) vv[n] = y[m][n] * 0.125f;
    float s = vv[0] + vv[1] + vv[2] + vv[3];
    float s2 = vv[0]*vv[0] + vv[1]*vv[1] + vv[2]*vv[2] + vv[3]*vv[3];
    s += __shfl_xor(s, 1);  s2 += __shfl_xor(s2, 1);
    s += __shfl_xor(s, 2);  s2 += __shfl_xor(s2, 2);
    s += __shfl_xor(s, 4);  s2 += __shfl_xor(s2, 4);
    s += __shfl_xor(s, 8);  s2 += __shfl_xor(s2, 8);
    float mean = s * (1.f / 64.f);
    float var  = s2 * (1.f / 64.f) - mean * mean;
    float rstd = rsqrtf(fmaxf(var, 0.f) + LNEPS);
    size_t ob = ((size_t)(b * TT + c * 64 + t0 + m)) * CC + h * 64 + j0;
    ushort4 gt = *(const ushort4*)(gate + ob);
    ushort4 ou;
    ou.x = f2bf(((vv[0] - mean) * rstd * g4[0] + b4[0]) * bf2f(gt.x));
    ou.y = f2bf(((vv[1] - mean) * rstd * g4[1] + b4[1]) * bf2f(gt.y));
    ou.z = f2bf(((vv[2] - mean) * rstd * g4[2] + b4[2]) * bf2f(gt.z));
    ou.w = f2bf(((vv[3] - mean) * rstd * g4[3] + b4[3]) * bf2f(gt.w));
    *(ushort4*)(outp + ob) = ou;
  }
}

// ---------------- launch ----------------
extern "C" void kernel_launch(void* const* d_in, const int* in_sizes, int n_in,
                              void* d_out, int out_size, void* d_ws, size_t ws_size,
                              hipStream_t stream)
{
  const void* x    = d_in[0];
  const void* ln1g = d_in[1];
  const void* ln1b = d_in[2];
  const void* ln2g = d_in[3];
  const void* ln2b = d_in[4];
  const void* tmk  = d_in[5];
  const void* tmv  = d_in[6];
  const void* tmr  = d_in[7];
  const void* tmg  = d_in[8];
  const void* tdec = d_in[9];
  const void* tfaa = d_in[10];
  const void* Wr   = d_in[11];
  const void* Wk   = d_in[12];
  const void* Wv   = d_in[13];
  const void* Wg   = d_in[14];
  const void* Wo   = d_in[15];
  const void* lnxg = d_in[16];
  const void* lnxb = d_in[17];
  const void* fmk  = d_in[18];
  const void* fmr  = d_in[19];
  const void* Wkey = d_in[20];
  const void* Wrec = d_in[21];
  const void* Wval = d_in[22];

  char* ws = (char*)d_ws;
  const size_t SL  = (size_t)MTOT * CC;
  uint16_t* XL    = (uint16_t*)(ws + 0);            // 8 MiB: xl / xl2 / WrecT / P3-lo
  uint16_t* WRECT = XL;                             // alias (xl2 dead after mix2)
  uint16_t* MIX4  = (uint16_t*)(ws + 8388608);      // 32 MiB: mixes / PART P0,P1
  float*    PART  = (float*)   (ws + 8388608);      // alias (ck dead after FF gemms)
  uint16_t* RKVG  = (uint16_t*)(ws + 41943040);     // 32 MiB: r,k,v,g / cr / sr / P2,P3-hi
  float*    X1    = (float*)   (ws + 75497472);     // 16 MiB (Wo residual output, f32)
  float*    Pb    = (float*)   (ws + 92274688);     // 16 MiB
  float*    Sb    = (float*)   (ws + 109051904);    // 16 MiB
  uint16_t* KK    = (uint16_t*)(ws + 92274688);     // 32 MiB, alias P+S (dead)
  uint16_t* WT    = (uint16_t*)(ws + 125829120);    // 32 MiB
  int*      FLAG  = (int*)     (ws + 159383552);
  (void)in_sizes; (void)n_in; (void)out_size; (void)ws_size;

  // 0. dtype probe
  probe_kernel<<<dim3(1), 64, 0, stream>>>((const uint16_t*)x, FLAG);
  // 1. LN1
  ln_kernel<0><<<dim3(MTOT), 256, 0, stream>>>(x, ln1g, ln1b, XL, FLAG);
  // 2. transposes Wr,Wk,Wv,Wg -> WT slots 0..3 (one launch)
  transpose4_kernel<<<dim3(32, 32, 4), 256, 0, stream>>>(Wr, Wk, Wv, Wg, WT, FLAG);
  // 3. mixes (slices r,k,v,g)
  mix4_kernel<<<dim3(2048), 256, 0, stream>>>(XL, tmr, tmk, tmv, tmg, MIX4, FLAG);
  // 4. batched GEMM: r,k,v,g (silu on g) -- 256^2, 256 blocks, cx=8
  gemm256_kernel<G_RKVG><<<dim3(8, 8, 4), 512, 0, stream>>>(MIX4, WT, (void*)RKVG, CC, CC, CC, 8,
      nullptr, nullptr, nullptr);
  // 5. WKV5 chunked; wkv_y now fuses GroupNorm(att/8)*gate -> MIX4 slot0 (bf16)
  wkv_p_kernel<<<dim3(1024), 256, 0, stream>>>(RKVG + 1 * SL, RKVG + 2 * SL, tdec, Pb, FLAG);
  wkv_s_kernel<<<dim3(256), 256, 0, stream>>>(Pb, tdec, Sb, FLAG);
  wkv_y_kernel<<<dim3(1024), 256, 0, stream>>>(RKVG + 0 * SL, RKVG + 1 * SL, RKVG + 2 * SL,
      tdec, tfaa, Sb, lnxg, lnxb, RKVG + 3 * SL, MIX4, FLAG);
  // 7. Wo GEMM + residual -> X1 (f32)  (64 tiles only at 256^2 -> keep 128^2 kernel)
  transpose_kernel<<<dim3(32, 32), 256, 0, stream>>>(Wo, WT, CC, CC, FLAG);
  gemm_kernel<EPI_RESID><<<dim3(16, 16), 256, 0, stream>>>(MIX4, WT, (void*)X1, CC, CC, CC,
      x, FLAG);
  // 8. LN2 -> XL (reuse)
  ln_kernel<1><<<dim3(MTOT), 256, 0, stream>>>(X1, ln2g, ln2b, XL, FLAG);
  // 9. mixes ck (MIX4 slot0), cr (RKVG slot0)
  mix2_kernel<<<dim3(2048), 256, 0, stream>>>(XL, fmk, fmr, MIX4, RKVG, FLAG);
  // 10. transposes for FF: Wkey -> WT AND Wrec -> WRECT in ONE launch
  transpose_ff_kernel<<<dim3(FFD / 64 + 32, CC / 64), 256, 0, stream>>>(Wkey, Wrec, WT, WRECT, FLAG);
  // 11a. kk = relu(ck@Wkey)^2 -- 256^2, 32x8 = 256 blocks, cx=4
  gemm256_kernel<G_KK><<<dim3(32, 8), 512, 0, stream>>>(MIX4, WT, (void*)KK, FFD, CC, CC, 4,
      nullptr, nullptr, nullptr);
  // 11b. sr = sigmoid(cr@Wrec) -> RKVG slot2 (128^2 kernel: full grid at this size)
  gemm_kernel<EPI_SIGM><<<dim3(16, 16), 256, 0, stream>>>(RKVG, WRECT, (void*)(RKVG + 2 * SL), CC, CC, CC,
      nullptr, FLAG);
  // 12. Wval GEMM split-K=4 -- 256^2, 8x8x4 = 256 blocks, cx=8.
  //     Partials (f32, 4 x 16.78 MB) in dead regions: P0,P1 = MIX4; P2 = RKVG slots0-1;
  //     P3 = XL (rows 0..1023) + RKVG slot3 (rows 1024..2047). sr/X1/KK/WT untouched.
  transpose_kernel<<<dim3(CC / 64, FFD / 64), 256, 0, stream>>>(Wval, WT, FFD, CC, FLAG);
  gemm256_kernel<G_PART><<<dim3(8, 8, 4), 512, 0, stream>>>(KK, WT, (void*)PART, CC, FFD, FFD / 4, 8,
      (float*)RKVG, (float*)XL, (float*)(RKVG + 3 * SL));
  // 13. reduce: out = X1 + sr * (P0 + P1 + P2 + P3)
  final_reduce_kernel<<<dim3(2048), 256, 0, stream>>>(PART, X1, RKVG + 2 * SL, d_out,
      (float*)RKVG, (float*)XL, (float*)(RKVG + 3 * SL), FLAG);
}

// Round 10
// 660.750 us; speedup vs baseline: 1.4644x; 1.4644x over previous
//
#include <hip/hip_runtime.h>
#include <stdint.h>

#define BB 2
#define TT 1024
#define CC 2048
#define HH 32
#define NNH 64
#define FFD 8192
#define MTOT (BB*TT)    // 2048 rows
#define LNEPS 1e-5f
#define LOG2E 1.44269504088896340736f

typedef __attribute__((ext_vector_type(8))) __bf16 bf16x8;
typedef __attribute__((ext_vector_type(4))) float f32x4;

#define USE_GLL 1
typedef __attribute__((address_space(1))) void GAS;
typedef __attribute__((address_space(3))) void LAS;

__device__ inline void gload_lds16(const uint16_t* g, uint16_t* l) {
#if USE_GLL
  __builtin_amdgcn_global_load_lds((GAS*)g, (LAS*)l, 16, 0, 0);
#else
  *(uint4*)l = *(const uint4*)g;
#endif
}

__device__ inline float bf2f(uint32_t u) {
  union { uint32_t i; float f; } v; v.i = u << 16; return v.f;
}
__device__ inline uint16_t f2bf(float f) {
  union { float f; uint32_t i; } v; v.f = f;
  uint32_t r = v.i + 0x7FFFu + ((v.i >> 16) & 1u);
  return (uint16_t)(r >> 16);
}
__device__ inline void unpack8(uint4 d, float* v) {
  v[0] = bf2f(d.x & 0xffffu); v[1] = bf2f(d.x >> 16);
  v[2] = bf2f(d.y & 0xffffu); v[3] = bf2f(d.y >> 16);
  v[4] = bf2f(d.z & 0xffffu); v[5] = bf2f(d.z >> 16);
  v[6] = bf2f(d.w & 0xffffu); v[7] = bf2f(d.w >> 16);
}
__device__ inline uint4 pack8(const float* v) {
  uint4 d;
  d.x = (uint32_t)f2bf(v[0]) | ((uint32_t)f2bf(v[1]) << 16);
  d.y = (uint32_t)f2bf(v[2]) | ((uint32_t)f2bf(v[3]) << 16);
  d.z = (uint32_t)f2bf(v[4]) | ((uint32_t)f2bf(v[5]) << 16);
  d.w = (uint32_t)f2bf(v[6]) | ((uint32_t)f2bf(v[7]) << 16);
  return d;
}

// flag-aware loads for d_in buffers (fl=1 -> fp32, fl=0 -> bf16)
__device__ inline void load8f(const void* p, size_t idx, int fl, float* v) {
  if (fl) {
    const float* q = (const float*)p + idx;
    float4 a = *(const float4*)q; float4 b = *(const float4*)(q + 4);
    v[0]=a.x; v[1]=a.y; v[2]=a.z; v[3]=a.w; v[4]=b.x; v[5]=b.y; v[6]=b.z; v[7]=b.w;
  } else {
    unpack8(*(const uint4*)((const uint16_t*)p + idx), v);
  }
}
__device__ inline float load1f(const void* p, size_t idx, int fl) {
  return fl ? ((const float*)p)[idx] : bf2f(((const uint16_t*)p)[idx]);
}

// ---------------- dtype probe ----------------
__global__ void probe_kernel(const uint16_t* __restrict__ x, int* __restrict__ flag) {
  int tid = threadIdx.x; // 64
  float m = 0.f;
  for (int i = tid; i < 4096; i += 64) {
    float a = fabsf(bf2f(x[i]));
    if (a > m) m = a;
  }
  for (int o = 32; o; o >>= 1) { float t = __shfl_down(m, o); if (t > m) m = t; }
  if (tid == 0) *flag = (m > 1e6f) ? 1 : 0;
}

// ---------------- LayerNorm ----------------
template<int INMODE>
__global__ __launch_bounds__(256) void ln_kernel(const void* __restrict__ x,
    const void* __restrict__ g, const void* __restrict__ b,
    uint16_t* __restrict__ out, const int* __restrict__ dflag)
{
  int fl = *dflag;
  int row = blockIdx.x;
  int tid = threadIdx.x;
  int lane = tid & 63, wave = tid >> 6;
  size_t base = (size_t)row * CC + (size_t)tid * 8;
  float v[8];
  if constexpr (INMODE == 1) {
    const float* q = (const float*)x + base;
    float4 a = *(const float4*)q; float4 c = *(const float4*)(q + 4);
    v[0]=a.x; v[1]=a.y; v[2]=a.z; v[3]=a.w; v[4]=c.x; v[5]=c.y; v[6]=c.z; v[7]=c.w;
  } else {
    load8f(x, base, fl, v);
  }
  float s = 0.f, s2 = 0.f;
  #pragma unroll
  for (int j = 0; j < 8; j++) { s += v[j]; s2 += v[j] * v[j]; }
  for (int o = 32; o; o >>= 1) { s += __shfl_down(s, o); s2 += __shfl_down(s2, o); }
  __shared__ float red[8];
  if (lane == 0) { red[wave] = s; red[wave + 4] = s2; }
  __syncthreads();
  s  = red[0] + red[1] + red[2] + red[3];
  s2 = red[4] + red[5] + red[6] + red[7];
  float mean = s * (1.0f / CC);
  float var  = s2 * (1.0f / CC) - mean * mean;
  float rstd = rsqrtf(fmaxf(var, 0.f) + LNEPS);
  float gj[8], bj[8];
  load8f(g, (size_t)tid * 8, fl, gj);
  load8f(b, (size_t)tid * 8, fl, bj);
  float o8[8];
  #pragma unroll
  for (int j = 0; j < 8; j++) o8[j] = (v[j] - mean) * rstd * gj[j] + bj[j];
  *(uint4*)(out + base) = pack8(o8);
}

// ---------------- time-shift mixes ----------------
__global__ __launch_bounds__(256) void mix4_kernel(const uint16_t* __restrict__ xl,
    const void* __restrict__ tmr, const void* __restrict__ tmk,
    const void* __restrict__ tmv, const void* __restrict__ tmg,
    uint16_t* __restrict__ out, const int* __restrict__ dflag)
{
  int fl = *dflag;
  uint32_t idx = ((uint32_t)blockIdx.x * 256u + threadIdx.x) * 8u;
  uint32_t c = idx & (CC - 1);
  uint32_t row = idx >> 11;
  uint32_t t = row & (TT - 1);
  float xv[8], pv[8];
  unpack8(*(const uint4*)(xl + idx), xv);
  if (t) { unpack8(*(const uint4*)(xl + idx - CC), pv); }
  else   { for (int j = 0; j < 8; j++) pv[j] = 0.f; }
  const void* tms[4] = { tmr, tmk, tmv, tmg };
  const size_t SL = (size_t)MTOT * CC;
  #pragma unroll
  for (int a = 0; a < 4; a++) {
    float tm[8], o[8];
    load8f(tms[a], c, fl, tm);
    #pragma unroll
    for (int j = 0; j < 8; j++) o[j] = xv[j] * tm[j] + pv[j] * (1.f - tm[j]);
    *(uint4*)(out + a * SL + idx) = pack8(o);
  }
}

__global__ __launch_bounds__(256) void mix2_kernel(const uint16_t* __restrict__ xl,
    const void* __restrict__ tk, const void* __restrict__ tr,
    uint16_t* __restrict__ ok, uint16_t* __restrict__ orr,
    const int* __restrict__ dflag)
{
  int fl = *dflag;
  uint32_t idx = ((uint32_t)blockIdx.x * 256u + threadIdx.x) * 8u;
  uint32_t c = idx & (CC - 1);
  uint32_t row = idx >> 11;
  uint32_t t = row & (TT - 1);
  float xv[8], pv[8], tm[8], o[8];
  unpack8(*(const uint4*)(xl + idx), xv);
  if (t) { unpack8(*(const uint4*)(xl + idx - CC), pv); }
  else   { for (int j = 0; j < 8; j++) pv[j] = 0.f; }
  load8f(tk, c, fl, tm);
  #pragma unroll
  for (int j = 0; j < 8; j++) o[j] = xv[j] * tm[j] + pv[j] * (1.f - tm[j]);
  *(uint4*)(ok + idx) = pack8(o);
  load8f(tr, c, fl, tm);
  #pragma unroll
  for (int j = 0; j < 8; j++) o[j] = xv[j] * tm[j] + pv[j] * (1.f - tm[j]);
  *(uint4*)(orr + idx) = pack8(o);
}

// ---------------- weight transpose: W (Kd x Nd, d_in dtype) -> WT (Nd x Kd, bf16) ----------------
__device__ inline void transpose_tile(const void* W, uint16_t* WT, int Kd, int Nd,
                                      int n0, int k0, int fl, int tid)
{
  __shared__ __align__(16) uint16_t tile[64][66];
  int r = tid >> 3, s = tid & 7;
  #pragma unroll
  for (int p = 0; p < 2; p++) {
    int row = p * 32 + r;
    float tv[8];
    load8f(W, (size_t)(k0 + row) * Nd + n0 + s * 8, fl, tv);
    uint16_t* t = &tile[row][s * 8];
    #pragma unroll
    for (int e = 0; e < 8; e++) t[e] = f2bf(tv[e]);
  }
  __syncthreads();
  #pragma unroll
  for (int p = 0; p < 2; p++) {
    int row = p * 32 + r;
    uint16_t tmp[8];
    #pragma unroll
    for (int e = 0; e < 8; e++) tmp[e] = tile[s * 8 + e][row];
    uint4 o;
    o.x = (uint32_t)tmp[0] | ((uint32_t)tmp[1] << 16);
    o.y = (uint32_t)tmp[2] | ((uint32_t)tmp[3] << 16);
    o.z = (uint32_t)tmp[4] | ((uint32_t)tmp[5] << 16);
    o.w = (uint32_t)tmp[6] | ((uint32_t)tmp[7] << 16);
    *(uint4*)(WT + (size_t)(n0 + row) * Kd + k0 + s * 8) = o;
  }
}

__global__ __launch_bounds__(256) void transpose_kernel(const void* __restrict__ W,
    uint16_t* __restrict__ WT, int Kd, int Nd, const int* __restrict__ dflag)
{
  transpose_tile(W, WT, Kd, Nd, blockIdx.x * 64, blockIdx.y * 64, *dflag, threadIdx.x);
}

// 4 square CCxCC transposes in one launch (z selects)
__global__ __launch_bounds__(256) void transpose4_kernel(
    const void* __restrict__ W0, const void* __restrict__ W1,
    const void* __restrict__ W2, const void* __restrict__ W3,
    uint16_t* __restrict__ WT, const int* __restrict__ dflag)
{
  const void* Ws[4] = { W0, W1, W2, W3 };
  int z = blockIdx.z;
  transpose_tile(Ws[z], WT + (size_t)z * CC * CC, CC, CC,
                 blockIdx.x * 64, blockIdx.y * 64, *dflag, threadIdx.x);
}

// Wkey (2048x8192) -> WT  and  Wrec (2048x2048) -> WRECT, one launch (bx selects)
__global__ __launch_bounds__(256) void transpose_ff_kernel(
    const void* __restrict__ Wkey, const void* __restrict__ Wrec,
    uint16_t* __restrict__ WT, uint16_t* __restrict__ WRECT,
    const int* __restrict__ dflag)
{
  int fl = *dflag;
  int bx = blockIdx.x;
  if (bx < FFD / 64) {
    transpose_tile(Wkey, WT, CC, FFD, bx * 64, blockIdx.y * 64, fl, threadIdx.x);
  } else {
    transpose_tile(Wrec, WRECT, CC, CC, (bx - FFD / 64) * 64, blockIdx.y * 64, fl, threadIdx.x);
  }
}

// ---------------- small-tile GEMM (128x128, kept for low-parallelism cases) ----------------
enum { EPI_RESID = 2, EPI_SIGM = 9 };

template<int EPI>
__global__ __launch_bounds__(256, 2) void gemm_kernel(
    const uint16_t* __restrict__ Ain, const uint16_t* __restrict__ BTin,
    void* __restrict__ Cout, int N, int Kstride, int Kloop,
    const void* __restrict__ auxA, const int* __restrict__ dflag)
{
  const uint16_t* A  = Ain;
  const uint16_t* BT = BTin;
  uint16_t* co16 = (uint16_t*)Cout;
  float*    co32 = (float*)Cout;
  int fl = 0;
  if constexpr (EPI == EPI_RESID) fl = *dflag;
  int bx = blockIdx.x;
  int N_ = N;
  int n0 = bx * 128;
  int m0 = blockIdx.y * 128;
  __shared__ __align__(16) uint16_t As[128 * 64];
  __shared__ __align__(16) uint16_t Bs[128 * 64];
  int tid = threadIdx.x;
  int lane = tid & 63, wave = tid >> 6;
  int wm = (wave >> 1) * 64, wn = (wave & 1) * 64;
  int l15 = lane & 15, lq = lane >> 4;
  int sw = l15 & 7;
  f32x4 acc[4][4];
  #pragma unroll
  for (int i = 0; i < 4; i++)
    #pragma unroll
    for (int j = 0; j < 4; j++) acc[i][j] = 0.f;
  const int rr = tid >> 3, seg = tid & 7;
  const int sseg = (seg ^ (rr & 7)) * 8;   // swizzled k-group source
  const uint16_t* Ag = A + (size_t)(m0 + rr) * Kstride + sseg;
  const uint16_t* Bg = BT + (size_t)(n0 + rr) * Kstride + sseg;
  uint16_t* Asw = As + tid * 8;
  uint16_t* Bsw = Bs + tid * 8;
  for (int k0 = 0; k0 < Kloop; k0 += 64) {
    __syncthreads();
    #pragma unroll
    for (int p = 0; p < 4; p++) {
      gload_lds16(Ag + (size_t)p * 32 * Kstride + k0, Asw + p * 2048);
      gload_lds16(Bg + (size_t)p * 32 * Kstride + k0, Bsw + p * 2048);
    }
    __syncthreads();
    #pragma unroll
    for (int kk = 0; kk < 2; kk++) {
      int cidx = ((kk * 4 + lq) ^ sw) * 8;
      bf16x8 af[4], bv[4];
      #pragma unroll
      for (int f = 0; f < 4; f++) af[f] = *(const bf16x8*)&As[(wm + f * 16 + l15) * 64 + cidx];
      #pragma unroll
      for (int f = 0; f < 4; f++) bv[f] = *(const bf16x8*)&Bs[(wn + f * 16 + l15) * 64 + cidx];
      #pragma unroll
      for (int fm = 0; fm < 4; fm++)
        #pragma unroll
        for (int fn = 0; fn < 4; fn++)
          acc[fm][fn] = __builtin_amdgcn_mfma_f32_16x16x32_bf16(af[fm], bv[fn], acc[fm][fn], 0, 0, 0);
    }
  }
  #pragma unroll
  for (int fm = 0; fm < 4; fm++) {
    #pragma unroll
    for (int q = 0; q < 4; q++) {
      int gr = m0 + wm + fm * 16 + lq * 4 + q;
      size_t rowb = (size_t)gr * N_;
      #pragma unroll
      for (int fn = 0; fn < 4; fn++) {
        int gc = n0 + wn + fn * 16 + l15;
        size_t idx = rowb + gc;
        float val = acc[fm][fn][q];
        if constexpr (EPI == EPI_RESID) {
          co32[idx] = val + load1f(auxA, idx, fl);
        } else if constexpr (EPI == EPI_SIGM) {
          co16[idx] = f2bf(1.f / (1.f + __expf(-val)));
        }
      }
    }
  }
}

// ---------------- 256x256 4-barrier GEMM (T1..T5, plain HIP) ----------------
// BM=BN=256, BK=64, 8 waves (2M x 4N), 512 threads, 128 KiB LDS (2 dbuf x (A 32KB + B 32KB)).
// Quadrants per K-tile: Q1=(M0,N0) Q2=(M0,N1) Q3=(M1,N1) Q4=(M1,N0).
// Byte-identical to R6/R8 -- this kernel is the ENVIRONMENT PROBE. Identical ISA measured
// 71.7 us (R6) vs 104.9 us (R8): some sessions' chips run compute-bound code ~1.45x slower
// (memory-bound kernels unaffected). Expect ~72 us healthy / ~105 slow; don't attribute to code.
// R6 (kept): only the END-of-phase barrier (4 barriers/K-tile) -- waves skew inside a
// phase so early waves' MFMAs overlap late waves' LDS reads. +3% measured, refcheck'd.
// WAR ledger (end-of-phase barriers only):
//   A-h0(d): read P1 (drained pre-Q1), staged P2 (after P1-end bar) OK
//   B-h0(d): read P1 (drained pre-Q1), staged P3 OK
//   B-h1(d): read P1, drained pre-Q2 (P2), staged P4 (after P3-end bar) OK
//   A-h1(d^1): read P3 of t-1 (drained pre-Q3), staged P1 of t (after P4-end bar of t-1) OK
// RAW: boundary vmcnt(6) + P4-end barrier -- all of tile t+1 resident before any wave
// enters tile t+1; 6 of t+2's loads stay in flight.
// XCD swizzle (T1): measured FETCH 147.6 -> 49.3 MB. LDS XOR swizzle (T2): 0 bank conflicts.
enum { G_RKVG = 0, G_KK = 1, G_PART = 2 };

template<int EPI>
__global__ __launch_bounds__(512, 2) void gemm256_kernel(
    const uint16_t* __restrict__ Ain, const uint16_t* __restrict__ BTin,
    void* __restrict__ Cout, int N, int Kstride, int Kloop, int cx,
    float* __restrict__ p2, float* __restrict__ p3a, float* __restrict__ p3b)
{
  __shared__ __align__(16) uint16_t smem[65536];   // A: [0,32768) B: [32768,65536) elements
  const uint16_t* A  = Ain;
  const uint16_t* BT = BTin;
  uint16_t* co16 = (uint16_t*)Cout;
  float*    co32 = (float*)Cout;

  // ---- XCD-aware bijective remap (nwg == 256 for all call sites) ----
  uint32_t lid = ((uint32_t)blockIdx.z * gridDim.y + blockIdx.y) * gridDim.x + blockIdx.x;
  uint32_t xcd = lid & 7u, s = lid >> 3;          // s in [0,32)
  uint32_t lx = s % (uint32_t)cx, ly = s / (uint32_t)cx;
  uint32_t sx = gridDim.x / (uint32_t)cx;         // chunks along x
  uint32_t cxi = xcd % sx, cyi = xcd / sx;
  uint32_t gx  = cxi * (uint32_t)cx + lx;         // n-tile
  uint32_t gyz = cyi * (32u / (uint32_t)cx) + ly; // flattened (z*GY + y)
  uint32_t gy  = gyz % gridDim.y;
  uint32_t z   = gyz / gridDim.y;

  int n0 = (int)gx * 256;
  int m0 = (int)gy * 256;
  bool silu = false;
  if constexpr (EPI == G_RKVG) {
    A    += (size_t)z * MTOT * CC;
    BT   += (size_t)z * CC * CC;
    co16 += (size_t)z * MTOT * CC;
    silu = (z == 3);
  }
  if constexpr (EPI == G_PART) {
    A  += (size_t)z * Kloop;      // column offset into K
    BT += (size_t)z * Kloop;
    if (z < 2)      co32 += (size_t)z * MTOT * 2048;
    else if (z == 2) co32 = p2;
    else            co32 = (m0 < 1024) ? p3a : (p3b - (size_t)1024 * 2048);
  }
  const int tid  = threadIdx.x;
  const int lane = tid & 63, wave = tid >> 6;
  const int wm = wave >> 2;          // 0..1
  const int wn = wave & 3;           // 0..3
  const int l15 = lane & 15, lq = lane >> 4;
  const int sw = l15 & 7;
  const int c0 = ((0 * 4 + lq) ^ sw) * 8;
  const int c1 = ((1 * 4 + lq) ^ sw) * 8;

  // staging addressing: thread covers rows (tid>>3) and (tid>>3)+64 of a 128-row half-tile,
  // segment tid&7, source k-group pre-swizzled by row&7 (row&7 == (tid>>3)&7 for both rows).
  const int trow = tid >> 3;
  const int tswz = ((tid & 7) ^ (trow & 7)) * 8;
  const uint16_t* Ag = A  + ((size_t)m0 + trow) * Kstride + tswz;
  const uint16_t* Bg = BT + ((size_t)n0 + trow) * Kstride + tswz;
  uint16_t* ldsT = smem + tid * 8;
  const size_t r64K = (size_t)64 * Kstride;

  const uint16_t* aRd = smem + (wm * 64 + l15) * 64;
  const uint16_t* bRd = smem + 32768 + (wn * 32 + l15) * 64;

  bf16x8 a[4][2];
  bf16x8 bb[2][2][2];
  f32x4  acc[2][4][2][2];
  #pragma unroll
  for (int mh = 0; mh < 2; mh++)
    #pragma unroll
    for (int f = 0; f < 4; f++)
      #pragma unroll
      for (int nh = 0; nh < 2; nh++)
        #pragma unroll
        for (int g = 0; g < 2; g++) acc[mh][f][nh][g] = 0.f;

#define STG(Mg, matOff, d, h, kt) do { \
    const uint16_t* s_ = (Mg) + (size_t)((h) * 128) * Kstride + (size_t)(kt) * 64; \
    uint16_t* l_ = ldsT + (matOff) + (d) * 16384 + (h) * 8192; \
    gload_lds16(s_, l_); \
    gload_lds16(s_ + r64K, l_ + 4096); \
  } while (0)

#define RD_A(mh, d) do { \
    const uint16_t* p_ = aRd + (d) * 16384 + (mh) * 8192; \
    _Pragma("unroll") \
    for (int f = 0; f < 4; f++) { \
      a[f][0] = *(const bf16x8*)(p_ + f * 1024 + c0); \
      a[f][1] = *(const bf16x8*)(p_ + f * 1024 + c1); \
    } \
  } while (0)

#define RD_B(nh, d) do { \
    const uint16_t* p_ = bRd + (d) * 16384 + (nh) * 8192; \
    _Pragma("unroll") \
    for (int g = 0; g < 2; g++) { \
      bb[nh][g][0] = *(const bf16x8*)(p_ + g * 1024 + c0); \
      bb[nh][g][1] = *(const bf16x8*)(p_ + g * 1024 + c1); \
    } \
  } while (0)

#define QUAD(mh, nh) do { \
    __builtin_amdgcn_s_setprio(1); \
    _Pragma("unroll") \
    for (int f = 0; f < 4; f++) \
      _Pragma("unroll") \
      for (int g = 0; g < 2; g++) { \
        acc[mh][f][nh][g] = __builtin_amdgcn_mfma_f32_16x16x32_bf16(a[f][0], bb[nh][g][0], acc[mh][f][nh][g], 0, 0, 0); \
        acc[mh][f][nh][g] = __builtin_amdgcn_mfma_f32_16x16x32_bf16(a[f][1], bb[nh][g][1], acc[mh][f][nh][g], 0, 0, 0); \
      } \
    __builtin_amdgcn_s_setprio(0); \
  } while (0)

#define TILE(t, d) do { \
    /* P1: Q1=(M0,N0) -- read a0/b0 (needed) then b1 early; stage t+1.A-h1 -> d^1 */ \
    RD_A(0, d); RD_B(0, d); \
    __builtin_amdgcn_sched_barrier(0); \
    RD_B(1, d); \
    if ((t) + 1 < NT) STG(Ag, 0, (d) ^ 1, 1, (t) + 1); \
    QUAD(0, 0); \
    __builtin_amdgcn_s_barrier(); \
    /* P2: Q2=(M0,N1) -- stage t+2.A-h0 (readers drained, certified by P1-end bar) */ \
    if ((t) + 2 < NT) STG(Ag, 0, d, 0, (t) + 2); \
    QUAD(0, 1); \
    __builtin_amdgcn_s_barrier(); \
    /* P3: Q3=(M1,N1) -- read A1; stage t+2.B-h0 (readers drained pre-Q1, cert. P1-end) */ \
    RD_A(1, d); \
    if ((t) + 2 < NT) STG(Bg, 32768, d, 0, (t) + 2); \
    QUAD(1, 1); \
    __builtin_amdgcn_s_barrier(); \
    /* P4: Q4=(M1,N0) -- bb[0] persists from P1; stage t+2.B-h1 (b1 drained pre-Q2) */ \
    if ((t) + 2 < NT) STG(Bg, 32768, d, 1, (t) + 2); \
    QUAD(1, 0); \
    if ((t) + 2 < NT)      { asm volatile("s_waitcnt vmcnt(6)" ::: "memory"); } \
    else if ((t) + 1 < NT) { asm volatile("s_waitcnt vmcnt(0)" ::: "memory"); } \
    __builtin_amdgcn_s_barrier(); \
  } while (0)

  const int NT = Kloop >> 6;   // always even (>= 32) for all call sites
  // prologue: tile0 fully (4 half-tiles) + tile1 partial (3; A-h1 deferred to ph1 of tile0)
  STG(Ag, 0, 0, 0, 0); STG(Ag, 0, 0, 1, 0);
  STG(Bg, 32768, 0, 0, 0); STG(Bg, 32768, 0, 1, 0);
  if (NT > 1) {
    STG(Ag, 0, 1, 0, 1); STG(Bg, 32768, 1, 0, 1); STG(Bg, 32768, 1, 1, 1);
    asm volatile("s_waitcnt vmcnt(6)" ::: "memory");   // tile0's 8 loads landed
  } else {
    asm volatile("s_waitcnt vmcnt(0)" ::: "memory");
  }
  __builtin_amdgcn_s_barrier();

  for (int t = 0; t < NT; t += 2) {
    TILE(t, 0);
    TILE(t + 1, 1);
  }

#undef TILE
#undef QUAD
#undef RD_B
#undef RD_A
#undef STG

  // epilogue
  #pragma unroll
  for (int mh = 0; mh < 2; mh++) {
    #pragma unroll
    for (int f = 0; f < 4; f++) {
      #pragma unroll
      for (int q = 0; q < 4; q++) {
        int gr = m0 + mh * 128 + wm * 64 + f * 16 + lq * 4 + q;
        size_t rowb = (size_t)gr * N;
        #pragma unroll
        for (int nh = 0; nh < 2; nh++) {
          #pragma unroll
          for (int g = 0; g < 2; g++) {
            int gc = n0 + nh * 128 + wn * 32 + g * 16 + l15;
            size_t idx = rowb + gc;
            float val = acc[mh][f][nh][g][q];
            if constexpr (EPI == G_RKVG) {
              if (silu) val = val / (1.f + __expf(-fmaxf(val, -80.f)));
              co16[idx] = f2bf(val);
            } else if constexpr (EPI == G_KK) {
              float tv = fmaxf(val, 0.f);
              co16[idx] = f2bf(tv * tv);
            } else if constexpr (EPI == G_PART) {
              co32[idx] = val;
            }
          }
        }
      }
    }
  }
}

// ---------------- split-K reduce + final epilogue ----------------
__global__ __launch_bounds__(256) void final_reduce_kernel(
    const float* __restrict__ P, const float* __restrict__ x1,
    const uint16_t* __restrict__ sr, void* __restrict__ out,
    const float* __restrict__ P2, const float* __restrict__ P3a,
    const float* __restrict__ P3b, const int* __restrict__ dflag)
{
  int fl = *dflag;
  size_t idx = ((size_t)blockIdx.x * 256 + threadIdx.x) * 8;
  const float* P1 = P + (size_t)MTOT * 2048;
  const float* P3 = (idx < (size_t)1024 * 2048) ? (P3a + idx) : (P3b + idx - (size_t)1024 * 2048);
  float a[8], b[8], c2[8], d3[8], xv[8], s8[8], o[8];
  { float4 t0 = *(const float4*)(P + idx);  float4 t1 = *(const float4*)(P + idx + 4);
    a[0]=t0.x;a[1]=t0.y;a[2]=t0.z;a[3]=t0.w;a[4]=t1.x;a[5]=t1.y;a[6]=t1.z;a[7]=t1.w; }
  { float4 t0 = *(const float4*)(P1 + idx); float4 t1 = *(const float4*)(P1 + idx + 4);
    b[0]=t0.x;b[1]=t0.y;b[2]=t0.z;b[3]=t0.w;b[4]=t1.x;b[5]=t1.y;b[6]=t1.z;b[7]=t1.w; }
  { float4 t0 = *(const float4*)(P2 + idx); float4 t1 = *(const float4*)(P2 + idx + 4);
    c2[0]=t0.x;c2[1]=t0.y;c2[2]=t0.z;c2[3]=t0.w;c2[4]=t1.x;c2[5]=t1.y;c2[6]=t1.z;c2[7]=t1.w; }
  { float4 t0 = *(const float4*)(P3);       float4 t1 = *(const float4*)(P3 + 4);
    d3[0]=t0.x;d3[1]=t0.y;d3[2]=t0.z;d3[3]=t0.w;d3[4]=t1.x;d3[5]=t1.y;d3[6]=t1.z;d3[7]=t1.w; }
  { float4 t0 = *(const float4*)(x1 + idx); float4 t1 = *(const float4*)(x1 + idx + 4);
    xv[0]=t0.x;xv[1]=t0.y;xv[2]=t0.z;xv[3]=t0.w;xv[4]=t1.x;xv[5]=t1.y;xv[6]=t1.z;xv[7]=t1.w; }
  unpack8(*(const uint4*)(sr + idx), s8);
  #pragma unroll
  for (int j = 0; j < 8; j++) o[j] = xv[j] + s8[j] * (a[j] + b[j] + c2[j] + d3[j]);
  if (fl) {
    float* q = (float*)out + idx;
    *(float4*)q = make_float4(o[0], o[1], o[2], o[3]);
    *(float4*)(q + 4) = make_float4(o[4], o[5], o[6], o[7]);
  } else {
    *(uint4*)((uint16_t*)out + idx) = pack8(o);
  }
}

// ---------------- WKV5 chunked ----------------
__global__ __launch_bounds__(256) void wkv_p_kernel(
    const uint16_t* __restrict__ kq, const uint16_t* __restrict__ vq,
    const void* __restrict__ wq, float* __restrict__ P,
    const int* __restrict__ dflag)
{
  int fl = *dflag;
  int blk = blockIdx.x;
  int c = blk & 15, h = (blk >> 4) & 31, b = blk >> 9;
  __shared__ __align__(16) float Kt[64][64];
  __shared__ __align__(16) uint16_t Vb[64][64];
  __shared__ __align__(16) float e_s[64];
  int tid = threadIdx.x;
  if (tid < 64) e_s[tid] = fminf(__expf(load1f(wq, h * 64 + tid, fl)), 100.f);
  __syncthreads();
  int rr = tid >> 3, cs = (tid & 7) * 8;
  #pragma unroll
  for (int p = 0; p < 2; p++) {
    int s = p * 32 + rr;
    size_t gbase = ((size_t)(b * TT + c * 64 + s)) * CC + h * 64 + cs;
    float k8[8];
    unpack8(*(const uint4*)(kq + gbase), k8);
    float sp = (float)(s + 1) * LOG2E;
    #pragma unroll
    for (int j = 0; j < 8; j++) Kt[s][cs + j] = k8[j] * exp2f(fminf(sp * e_s[cs + j], 80.f));
    *(uint4*)&Vb[s][cs] = *(const uint4*)(vq + gbase);
  }
  __syncthreads();
  int tx = tid & 15, ty = tid >> 4;
  int i0 = ty * 4, j0 = tx * 4;
  float acc[4][4] = {};
  for (int s = 0; s < 64; s++) {
    float4 a = *(const float4*)&Kt[s][i0];
    ushort4 vv = *(const ushort4*)&Vb[s][j0];
    float b0 = bf2f(vv.x), b1 = bf2f(vv.y), b2 = bf2f(vv.z), b3 = bf2f(vv.w);
    float am[4] = { a.x, a.y, a.z, a.w };
    #pragma unroll
    for (int m = 0; m < 4; m++) {
      acc[m][0] += am[m] * b0; acc[m][1] += am[m] * b1;
      acc[m][2] += am[m] * b2; acc[m][3] += am[m] * b3;
    }
  }
  float* Pb = P + (size_t)blk * 4096;
  #pragma unroll
  for (int m = 0; m < 4; m++) {
    float dl = exp2f(-64.0f * LOG2E * e_s[i0 + m]);
    float4 o = { acc[m][0] * dl, acc[m][1] * dl, acc[m][2] * dl, acc[m][3] * dl };
    *(float4*)&Pb[(i0 + m) * 64 + j0] = o;
  }
}

// parallel scan -- one float4 chain per thread, 256 blocks.
__global__ __launch_bounds__(256) void wkv_s_kernel(const float* __restrict__ P,
    const void* __restrict__ wq, float* __restrict__ S,
    const int* __restrict__ dflag)
{
  int fl = *dflag;
  int bh = blockIdx.x >> 2;      // 0..63
  int part = blockIdx.x & 3;     // 0..3
  int h = bh & 31;
  int tid = threadIdx.x;
  int e = part * 1024 + tid * 4; // float4 offset within 4096-elem state
  int i = e >> 6;                // state row (dl depends only on i)
  float ex = fminf(__expf(load1f(wq, h * 64 + i, fl)), 100.f);
  float dl = exp2f(-64.0f * LOG2E * ex);
  float4 s4 = {0.f, 0.f, 0.f, 0.f};
  size_t base = (size_t)bh * 16 * 4096 + e;
  #pragma unroll 4
  for (int c = 0; c < 16; c++) {
    *(float4*)&S[base] = s4;
    float4 p4 = *(const float4*)&P[base];
    s4 = make_float4(dl * s4.x + p4.x, dl * s4.y + p4.y, dl * s4.z + p4.z, dl * s4.w + p4.w);
    base += 4096;
  }
}

// Rt/Kt/Ss padded [64][64] -> [64][68] (R8 win, kept): kills the 16-way same-bank column
// read (bank was i%32 for all lanes at stride 64; stride 68 varies bank with row).
// R10: GN fusion REVERTED -- R9's in-register shuffle GN epilogue caused ~1 GB symmetric
// FETCH/WRITE (scratch spill signature), wkv_y 314 us. Back to separate gn_mul.
__global__ __launch_bounds__(256, 2) void wkv_y_kernel(
    const uint16_t* __restrict__ rq, const uint16_t* __restrict__ kq,
    const uint16_t* __restrict__ vq, const void* __restrict__ wq,
    const void* __restrict__ uq, const float* __restrict__ S,
    float* __restrict__ att, const int* __restrict__ dflag)
{
  int fl = *dflag;
  int blk = blockIdx.x;
  int c = blk & 15, h = (blk >> 4) & 31, b = blk >> 9;
  __shared__ __align__(16) float Rt[64][68];
  __shared__ __align__(16) float Kt[64][68];
  __shared__ __align__(16) uint16_t Vb[64][64];
  __shared__ __align__(16) float Ss[64][68];
  __shared__ __align__(16) float e_s[64];
  __shared__ __align__(16) float ud_s[64];
  int tid = threadIdx.x;
  if (tid < 64) {
    float e = fminf(__expf(load1f(wq, h * 64 + tid, fl)), 100.f);
    e_s[tid] = e;
    ud_s[tid] = load1f(uq, h * 64 + tid, fl) * __expf(-e);
  }
  __syncthreads();
  int rr = tid >> 3, cs = (tid & 7) * 8;
  #pragma unroll
  for (int p = 0; p < 2; p++) {
    int s = p * 32 + rr;
    size_t gbase = ((size_t)(b * TT + c * 64 + s)) * CC + h * 64 + cs;
    float r8[8], k8[8];
    unpack8(*(const uint4*)(rq + gbase), r8);
    unpack8(*(const uint4*)(kq + gbase), k8);
    float tneg = -(float)s * LOG2E;
    float spos = (float)(s + 1) * LOG2E;
    #pragma unroll
    for (int j = 0; j < 8; j++) {
      float e = e_s[cs + j];
      Rt[s][cs + j] = r8[j] * exp2f(tneg * e);
      Kt[s][cs + j] = k8[j] * exp2f(fminf(spos * e, 80.f));
    }
    *(uint4*)&Vb[s][cs] = *(const uint4*)(vq + gbase);
  }
  {
    int r2 = tid >> 2, q = tid & 3;
    const float* Sbp = S + (size_t)blk * 4096 + (size_t)r2 * 64 + q * 16;
    *(float4*)&Ss[r2][q * 16 + 0]  = *(const float4*)&Sbp[0];
    *(float4*)&Ss[r2][q * 16 + 4]  = *(const float4*)&Sbp[4];
    *(float4*)&Ss[r2][q * 16 + 8]  = *(const float4*)&Sbp[8];
    *(float4*)&Ss[r2][q * 16 + 12] = *(const float4*)&Sbp[12];
  }
  __syncthreads();
  int tx = tid & 15, ty = tid >> 4;
  int t0 = ty * 4, s0 = tx * 4;
  float acc[4][4] = {};
  for (int iq = 0; iq < 16; iq++) {
    int i = iq * 4;
    float4 ra[4], kb[4];
    #pragma unroll
    for (int m = 0; m < 4; m++) ra[m] = *(const float4*)&Rt[t0 + m][i];
    #pragma unroll
    for (int n = 0; n < 4; n++) kb[n] = *(const float4*)&Kt[s0 + n][i];
    #pragma unroll
    for (int m = 0; m < 4; m++)
      #pragma unroll
      for (int n = 0; n < 4; n++)
        acc[m][n] += ra[m].x * kb[n].x + ra[m].y * kb[n].y + ra[m].z * kb[n].z + ra[m].w * kb[n].w;
  }
  float dg = 0.f;
  if (tid < 64) {
    for (int iq = 0; iq < 16; iq++) {
      int i = iq * 4;
      float4 a = *(const float4*)&Rt[tid][i];
      float4 kk = *(const float4*)&Kt[tid][i];
      float4 u4 = *(const float4*)&ud_s[i];
      dg += a.x * kk.x * u4.x + a.y * kk.y * u4.y + a.z * kk.z * u4.z + a.w * kk.w * u4.w;
    }
  }
  __syncthreads();
  #pragma unroll
  for (int m = 0; m < 4; m++)
    #pragma unroll
    for (int n = 0; n < 4; n++) {
      int t = t0 + m, s = s0 + n;
      Kt[t][s] = (s < t) ? acc[m][n] : 0.0f;
    }
  __syncthreads();
  if (tid < 64) Kt[tid][tid] = dg;
  __syncthreads();
  int j0 = tx * 4;
  float y[4][4] = {};
  for (int sq = 0; sq < 16; sq++) {
    int s = sq * 4;
    float4 a4[4];
    #pragma unroll
    for (int m = 0; m < 4; m++) a4[m] = *(const float4*)&Kt[t0 + m][s];
    float vb[4][4];
    #pragma unroll
    for (int qq = 0; qq < 4; qq++) {
      ushort4 vv = *(const ushort4*)&Vb[s + qq][j0];
      vb[qq][0] = bf2f(vv.x); vb[qq][1] = bf2f(vv.y); vb[qq][2] = bf2f(vv.z); vb[qq][3] = bf2f(vv.w);
    }
    #pragma unroll
    for (int m = 0; m < 4; m++)
      #pragma unroll
      for (int n = 0; n < 4; n++)
        y[m][n] += a4[m].x * vb[0][n] + a4[m].y * vb[1][n] + a4[m].z * vb[2][n] + a4[m].w * vb[3][n];
  }
  for (int iq = 0; iq < 16; iq++) {
    int i = iq * 4;
    float4 r4[4], s4[4];
    #pragma unroll
    for (int m = 0; m < 4; m++) r4[m] = *(const float4*)&Rt[t0 + m][i];
    #pragma unroll
    for (int qq = 0; qq < 4; qq++) s4[qq] = *(const float4*)&Ss[i + qq][j0];
    #pragma unroll
    for (int m = 0; m < 4; m++)
      #pragma unroll
      for (int n = 0; n < 4; n++)
        y[m][n] += r4[m].x * s4[0][n] + r4[m].y * s4[1][n] + r4[m].z * s4[2][n] + r4[m].w * s4[3][n];
  }
  #pragma unroll
  for (int m = 0; m < 4; m++) {
    size_t ob = ((size_t)(b * TT + c * 64 + t0 + m)) * CC + h * 64 + j0;
    *(float4*)&att[ob] = make_float4(y[m][0], y[m][1], y[m][2], y[m][3]);
  }
}

// ---------------- GroupNorm(att/8) * g ----------------
__global__ __launch_bounds__(256) void gn_mul_kernel(const float* __restrict__ att,
    const void* __restrict__ gg, const void* __restrict__ bb,
    const uint16_t* __restrict__ gate, uint16_t* __restrict__ out,
    const int* __restrict__ dflag)
{
  int fl = *dflag;
  int row = blockIdx.x;
  int tid = threadIdx.x;
  size_t base = (size_t)row * CC + (size_t)tid * 8;
  float4 a0 = *(const float4*)(att + base);
  float4 a1 = *(const float4*)(att + base + 4);
  float v[8] = { a0.x, a0.y, a0.z, a0.w, a1.x, a1.y, a1.z, a1.w };
  #pragma unroll
  for (int j = 0; j < 8; j++) v[j] *= 0.125f;
  float s = 0.f, s2 = 0.f;
  #pragma unroll
  for (int j = 0; j < 8; j++) { s += v[j]; s2 += v[j] * v[j]; }
  s += __shfl_xor(s, 1); s += __shfl_xor(s, 2); s += __shfl_xor(s, 4);
  s2 += __shfl_xor(s2, 1); s2 += __shfl_xor(s2, 2); s2 += __shfl_xor(s2, 4);
  float m = s * (1.f / 64.f);
  float var = s2 * (1.f / 64.f) - m * m;
  float rstd = rsqrtf(fmaxf(var, 0.f) + LNEPS);
  int c = tid * 8;
  float g8[8], b8[8], gt8[8], o[8];
  load8f(gg, c, fl, g8);
  load8f(bb, c, fl, b8);
  unpack8(*(const uint4*)(gate + base), gt8);
  #pragma unroll
  for (int j = 0; j < 8; j++) o[j] = ((v[j] - m) * rstd * g8[j] + b8[j]) * gt8[j];
  *(uint4*)(out + base) = pack8(o);
}

// ---------------- launch ----------------
extern "C" void kernel_launch(void* const* d_in, const int* in_sizes, int n_in,
                              void* d_out, int out_size, void* d_ws, size_t ws_size,
                              hipStream_t stream)
{
  const void* x    = d_in[0];
  const void* ln1g = d_in[1];
  const void* ln1b = d_in[2];
  const void* ln2g = d_in[3];
  const void* ln2b = d_in[4];
  const void* tmk  = d_in[5];
  const void* tmv  = d_in[6];
  const void* tmr  = d_in[7];
  const void* tmg  = d_in[8];
  const void* tdec = d_in[9];
  const void* tfaa = d_in[10];
  const void* Wr   = d_in[11];
  const void* Wk   = d_in[12];
  const void* Wv   = d_in[13];
  const void* Wg   = d_in[14];
  const void* Wo   = d_in[15];
  const void* lnxg = d_in[16];
  const void* lnxb = d_in[17];
  const void* fmk  = d_in[18];
  const void* fmr  = d_in[19];
  const void* Wkey = d_in[20];
  const void* Wrec = d_in[21];
  const void* Wval = d_in[22];

  char* ws = (char*)d_ws;
  const size_t SL  = (size_t)MTOT * CC;
  uint16_t* XL    = (uint16_t*)(ws + 0);            // 8 MiB: xl / xl2 / WrecT / P3-lo
  uint16_t* WRECT = XL;                             // alias (xl2 dead after mix2)
  uint16_t* MIX4  = (uint16_t*)(ws + 8388608);      // 32 MiB: mixes / PART P0,P1
  float*    PART  = (float*)   (ws + 8388608);      // alias (ck dead after FF gemms)
  uint16_t* RKVG  = (uint16_t*)(ws + 41943040);     // 32 MiB: r,k,v,g / cr / sr / P2,P3-hi
  float*    ATT   = (float*)   (ws + 75497472);     // 16 MiB (aliased as X1)
  float*    X1    = ATT;
  float*    Pb    = (float*)   (ws + 92274688);     // 16 MiB
  float*    Sb    = (float*)   (ws + 109051904);    // 16 MiB
  uint16_t* KK    = (uint16_t*)(ws + 92274688);     // 32 MiB, alias P+S (dead)
  uint16_t* WT    = (uint16_t*)(ws + 125829120);    // 32 MiB
  int*      FLAG  = (int*)     (ws + 159383552);
  (void)in_sizes; (void)n_in; (void)out_size; (void)ws_size;

  // 0. dtype probe
  probe_kernel<<<dim3(1), 64, 0, stream>>>((const uint16_t*)x, FLAG);
  // 1. LN1
  ln_kernel<0><<<dim3(MTOT), 256, 0, stream>>>(x, ln1g, ln1b, XL, FLAG);
  // 2. transposes Wr,Wk,Wv,Wg -> WT slots 0..3 (one launch)
  transpose4_kernel<<<dim3(32, 32, 4), 256, 0, stream>>>(Wr, Wk, Wv, Wg, WT, FLAG);
  // 3. mixes (slices r,k,v,g)
  mix4_kernel<<<dim3(2048), 256, 0, stream>>>(XL, tmr, tmk, tmv, tmg, MIX4, FLAG);
  // 4. batched GEMM: r,k,v,g (silu on g) -- 256^2, 256 blocks, cx=8
  gemm256_kernel<G_RKVG><<<dim3(8, 8, 4), 512, 0, stream>>>(MIX4, WT, (void*)RKVG, CC, CC, CC, 8,
      nullptr, nullptr, nullptr);
  // 5. WKV5 chunked
  wkv_p_kernel<<<dim3(1024), 256, 0, stream>>>(RKVG + 1 * SL, RKVG + 2 * SL, tdec, Pb, FLAG);
  wkv_s_kernel<<<dim3(256), 256, 0, stream>>>(Pb, tdec, Sb, FLAG);
  wkv_y_kernel<<<dim3(1024), 256, 0, stream>>>(RKVG + 0 * SL, RKVG + 1 * SL, RKVG + 2 * SL, tdec, tfaa, Sb, ATT, FLAG);
  // 6. GroupNorm(att/8)*g -> MIX4 slot0
  gn_mul_kernel<<<dim3(MTOT), 256, 0, stream>>>(ATT, lnxg, lnxb, RKVG + 3 * SL, MIX4, FLAG);
  // 7. Wo GEMM + residual -> X1 (f32)  (64 tiles only at 256^2 -> keep 128^2 kernel)
  transpose_kernel<<<dim3(32, 32), 256, 0, stream>>>(Wo, WT, CC, CC, FLAG);
  gemm_kernel<EPI_RESID><<<dim3(16, 16), 256, 0, stream>>>(MIX4, WT, (void*)X1, CC, CC, CC,
      x, FLAG);
  // 8. LN2 -> XL (reuse)
  ln_kernel<1><<<dim3(MTOT), 256, 0, stream>>>(X1, ln2g, ln2b, XL, FLAG);
  // 9. mixes ck (MIX4 slot0), cr (RKVG slot0)
  mix2_kernel<<<dim3(2048), 256, 0, stream>>>(XL, fmk, fmr, MIX4, RKVG, FLAG);
  // 10. transposes for FF: Wkey -> WT AND Wrec -> WRECT in ONE launch
  transpose_ff_kernel<<<dim3(FFD / 64 + 32, CC / 64), 256, 0, stream>>>(Wkey, Wrec, WT, WRECT, FLAG);
  // 11a. kk = relu(ck@Wkey)^2 -- 256^2, 32x8 = 256 blocks, cx=4
  gemm256_kernel<G_KK><<<dim3(32, 8), 512, 0, stream>>>(MIX4, WT, (void*)KK, FFD, CC, CC, 4,
      nullptr, nullptr, nullptr);
  // 11b. sr = sigmoid(cr@Wrec) -> RKVG slot2 (128^2 kernel: full grid at this size)
  gemm_kernel<EPI_SIGM><<<dim3(16, 16), 256, 0, stream>>>(RKVG, WRECT, (void*)(RKVG + 2 * SL), CC, CC, CC,
      nullptr, FLAG);
  // 12. Wval GEMM split-K=4 -- 256^2, 8x8x4 = 256 blocks, cx=8.
  //     Partials (f32, 4 x 16.78 MB) in dead regions: P0,P1 = MIX4; P2 = RKVG slots0-1;
  //     P3 = XL (rows 0..1023) + RKVG slot3 (rows 1024..2047). sr/X1/KK/WT untouched.
  transpose_kernel<<<dim3(CC / 64, FFD / 64), 256, 0, stream>>>(Wval, WT, FFD, CC, FLAG);
  gemm256_kernel<G_PART><<<dim3(8, 8, 4), 512, 0, stream>>>(KK, WT, (void*)PART, CC, FFD, FFD / 4, 8,
      (float*)RKVG, (float*)XL, (float*)(RKVG + 3 * SL));
  // 13. reduce: out = X1 + sr * (P0 + P1 + P2 + P3)
  final_reduce_kernel<<<dim3(2048), 256, 0, stream>>>(PART, X1, RKVG + 2 * SL, d_out,
      (float*)RKVG, (float*)XL, (float*)(RKVG + 3 * SL), FLAG);
}